// Round 8
// baseline (681.526 us; speedup 1.0000x reference)
//
#include <hip/hip_runtime.h>
#include <math.h>

typedef __attribute__((ext_vector_type(8))) short short8;
typedef __attribute__((ext_vector_type(4))) short short4_t;
typedef __attribute__((ext_vector_type(4))) float f32x4;

#define RS      312          // shorts per LDS tile row (624 B = 39*16B, 39%8=7)
#define EPS_OH  0.999f

__device__ __forceinline__ float waveSum(float v) {
#pragma unroll
  for (int off = 32; off; off >>= 1) v += __shfl_xor(v, off);
  return v;
}
__device__ __forceinline__ float waveMax(float v) {
#pragma unroll
  for (int off = 32; off; off >>= 1) v = fmaxf(v, __shfl_xor(v, off));
  return v;
}
__device__ __forceinline__ float leaky(float x) { return fmaxf(x, 0.1f * x); }

__device__ __forceinline__ short f2b(float f) {
  unsigned u = __float_as_uint(f);
  unsigned r = (u + 0x7FFFu + ((u >> 16) & 1u)) >> 16;
  return (short)r;
}
__device__ __forceinline__ float b2f(short h) {
  return __uint_as_float(((unsigned)(unsigned short)h) << 16);
}

// ---------------- question-side conv block (fp32, tiny), 8 lanes per output ----------------
__global__ __launch_bounds__(256) void qconv_kernel(
    const float* __restrict__ x, const float* __restrict__ W,
    const float* __restrict__ b, float* __restrict__ y)
{
  int idx = blockIdx.x * 256 + threadIdx.x;
  if (idx >= 76800) return;
  int part = idx & 7, gid = idx >> 3;
  int o = gid % 300, l = gid / 300;
  const float* Wo = W + o * 900;
  float acc = 0.f;
  for (int i = part; i < 300; i += 8) {
    float x1 = x[l * 300 + i];
    float x0 = (l >= 1) ? x[(l - 1) * 300 + i] : 0.f;
    float x2 = (l <= 30) ? x[(l + 1) * 300 + i] : 0.f;
    acc += Wo[i * 3] * x0 + Wo[i * 3 + 1] * x1 + Wo[i * 3 + 2] * x2;
  }
  acc += __shfl_xor(acc, 1);
  acc += __shfl_xor(acc, 2);
  acc += __shfl_xor(acc, 4);
  if (part == 0) y[gid] = leaky(acc + b[o]) + x[gid];
}

// ---------------- q_weights softmax + normalized q fragments (bf16 A-layout) ----------------
__global__ __launch_bounds__(256) void qfinish_kernel(
    const float* __restrict__ qemb, const float* __restrict__ qctx,
    const float* __restrict__ qidf, const float* __restrict__ qww,
    const float* __restrict__ qwb,
    float* __restrict__ qwv, short* __restrict__ qf)
{
  __shared__ float inq[32], inqc[32], lg[32];
  int tid = threadIdx.x, lane = tid & 63, w = tid >> 6;
  int r = w * 8 + (lane >> 3), sub = lane & 7;
  float sq = 0.f, sqc = 0.f, dt = 0.f;
  for (int i = sub; i < 300; i += 8) {
    float a = qemb[r * 300 + i]; sq  += a * a;
    float c = qctx[r * 300 + i]; sqc += c * c;
    dt += c * qww[i];
  }
#pragma unroll
  for (int off = 4; off; off >>= 1) {
    sq  += __shfl_xor(sq, off);
    sqc += __shfl_xor(sqc, off);
    dt  += __shfl_xor(dt, off);
  }
  if (sub == 0) {
    inq[r] = rsqrtf(sq); inqc[r] = rsqrtf(sqc);
    lg[r] = dt + qidf[r] * qww[300] + qwb[0];
  }
  __syncthreads();
  if (w == 0) {
    float L = (lane < 32) ? lg[lane] : -1e30f;
    float m = L;
#pragma unroll
    for (int off = 32; off; off >>= 1) m = fmaxf(m, __shfl_xor(m, off));
    float e = (lane < 32) ? expf(L - m) : 0.f;
    float ssum = e;
#pragma unroll
    for (int off = 32; off; off >>= 1) ssum += __shfl_xor(ssum, off);
    if (lane < 32) qwv[lane] = e / ssum;
  }
  __syncthreads();
  for (int t = tid; t < 2560; t += 256) {
    int ln = t & 63;
    int rest = t >> 6;
    int kt = rest % 10; rest /= 10;
    int mt = rest & 1; int sflag = rest >> 1;
    const float* src  = sflag ? qctx : qemb;
    const float* innv = sflag ? inqc : inq;
    int q  = mt * 16 + (ln & 15);
    int i0 = kt * 32 + (ln >> 4) * 8;
    float iv = innv[q];
    short8 v;
#pragma unroll
    for (int j = 0; j < 8; ++j) {
      int i = i0 + j;
      v[j] = f2b((i < 300) ? src[q * 300 + i] * iv : 0.f);
    }
    *(short8*)(qf + (size_t)t * 8) = v;
  }
}

// ---------------- W (300,300,3) fp32 -> bf16 A-fragment layout ----------------
__global__ __launch_bounds__(256) void wfrag_kernel(
    const float* __restrict__ W, short* __restrict__ Wf)
{
  int t = blockIdx.x * 256 + threadIdx.x;
  if (t >= 38400) return;
  int lane = t & 63;
  int rest = t >> 6;
  int mt = rest % 20; rest /= 20;
  int kt = rest % 10; int tap = rest / 10;
  int o  = mt * 16 + (lane & 15);
  int i0 = kt * 32 + (lane >> 4) * 8;
  short8 v;
#pragma unroll
  for (int j = 0; j < 8; ++j) {
    int i = i0 + j;
    v[j] = f2b((o < 300 && i < 300) ? W[o * 900 + i * 3 + tap] : 0.f);
  }
  *(short8*)(Wf + (size_t)t * 8) = v;
}

// ---------------- fused per-sentence-pair kernel helpers ----------------

// conv block for one sentence tile: dst[o][l] = bf16(leaky(GEMM+b)+src[o][l])
// wave role: mg (M-group: 5 mtiles), ng (N-half: positions ng*32..ng*32+31)
__device__ __forceinline__ void conv_mfma(
    const short* src, short* dst, const short* __restrict__ Wf,
    const float* __restrict__ bias, int mg, int ng, int r, int g, int lane)
{
  const int nmt = (mg < 3) ? 5 : 4;      // 19 mtiles total (mtile 19 all-zero, skipped)
  f32x4 acc[5][2];
#pragma unroll
  for (int mi = 0; mi < 5; ++mi) {
    acc[mi][0] = (f32x4){0.f, 0.f, 0.f, 0.f};
    acc[mi][1] = (f32x4){0.f, 0.f, 0.f, 0.f};
  }
  const int l0 = ng * 32 + r;            // nt2=0 position (0..47)
  const int l1 = l0 + 16;                // nt2=1 position (16..63)
  const int row0m = (l0 == 0) ? 0 : (l0 - 1);
  const int row1p = (l1 == 63) ? 63 : (l1 + 1);

#pragma unroll 2
  for (int kt = 0; kt < 10; ++kt) {
    const int koff = kt * 32 + g * 8;
    short8 b00 = *(const short8*)(src + row0m * RS + koff);      // tap0 nt0
    short8 b01 = *(const short8*)(src + (l0 + 0) * RS + koff);   // tap1 nt0
    short8 b02 = *(const short8*)(src + (l0 + 1) * RS + koff);   // tap2 nt0
    short8 b10 = *(const short8*)(src + (l1 - 1) * RS + koff);   // tap0 nt1
    short8 b11 = *(const short8*)(src + (l1 + 0) * RS + koff);   // tap1 nt1
    short8 b12 = *(const short8*)(src + row1p * RS + koff);      // tap2 nt1
    b00 = (l0 == 0)  ? (short8)0 : b00;
    b12 = (l1 == 63) ? (short8)0 : b12;
#pragma unroll
    for (int tap = 0; tap < 3; ++tap) {
      short8 bf0 = (tap == 0) ? b00 : ((tap == 1) ? b01 : b02);
      short8 bf1 = (tap == 0) ? b10 : ((tap == 1) ? b11 : b12);
      const short* wp = Wf + (size_t)(((tap * 10 + kt) * 20 + mg * 5) * 64 + lane) * 8;
#pragma unroll
      for (int mi = 0; mi < 5; ++mi) {
        if (mi < nmt) {
          short8 af = *(const short8*)(wp + mi * 512);
          acc[mi][0] = __builtin_amdgcn_mfma_f32_16x16x32_bf16(af, bf0, acc[mi][0], 0, 0, 0);
          acc[mi][1] = __builtin_amdgcn_mfma_f32_16x16x32_bf16(af, bf1, acc[mi][1], 0, 0, 0);
        }
      }
    }
  }
#pragma unroll
  for (int mi = 0; mi < 5; ++mi) {
    if (mi < nmt) {
      int m0 = (mg * 5 + mi) * 16 + g * 4;
      if (m0 < 300) {
        f32x4 bv = *(const f32x4*)(bias + m0);
#pragma unroll
        for (int nt2 = 0; nt2 < 2; ++nt2) {
          int l = ng * 32 + nt2 * 16 + r;
          short4_t resv = *(const short4_t*)(src + l * RS + m0);
          short4_t outv;
#pragma unroll
          for (int j = 0; j < 4; ++j) {
            float a = acc[mi][nt2][j] + bv[j];
            a = leaky(a) + b2f(resv[j]);
            outv[j] = f2b(a);
          }
          *(short4_t*)(dst + l * RS + m0) = outv;
        }
      }
    }
  }
}

// sim GEMM: one 16x16 tile per wave; SIMb[q][l] = normalized-q . src-col
__device__ __forceinline__ void sim_mfma(
    const short* src, const short* __restrict__ qf, float* SIMb,
    int ti, int r, int g, int lane)
{
  int smt = ti >> 2, snt = ti & 3;
  f32x4 acc = (f32x4){0.f, 0.f, 0.f, 0.f};
#pragma unroll
  for (int kt = 0; kt < 10; ++kt) {
    short8 bf = *(const short8*)(src + (snt * 16 + r) * RS + kt * 32 + g * 8);
    short8 af = *(const short8*)(qf + (size_t)((smt * 10 + kt) * 64 + lane) * 8);
    acc = __builtin_amdgcn_mfma_f32_16x16x32_bf16(af, bf, acc, 0, 0, 0);
  }
  int l = snt * 16 + r;
#pragma unroll
  for (int j = 0; j < 4; ++j)
    SIMb[(smt * 16 + g * 4 + j) * 68 + l] = acc[j];
}

// pooling for 4 q's per wave; writes feats directly (lane 0)
__device__ __forceinline__ void pool3(
    const float* SIMb, const float* invnp, float* featq,
    int q0, int lane, int foff, bool do_oh)
{
  float iv = invnp[lane];
#pragma unroll
  for (int qi = 0; qi < 4; ++qi) {
    int q = q0 + qi;
    float sim = SIMb[q * 68 + lane] * iv;
    float ssum = waveSum(sim);
    float vv = sim, tmax = 0.f, t5 = 0.f;
#pragma unroll
    for (int it = 0; it < 5; ++it) {
      float m = waveMax(vv);
      if (it == 0) tmax = m;
      t5 += m;
      unsigned long long bb = __ballot(vv == m);
      if (lane == (int)__builtin_ctzll(bb)) vv = -3e38f;
    }
    int c = 0;
    if (do_oh) c = __popcll(__ballot(sim > EPS_OH));
    if (lane == 0) {
      if (do_oh) {
        featq[q * 9 + 0] = (c > 0) ? 1.f : 0.f;
        featq[q * 9 + 1] = (c < 5 ? (float)c : 5.f) * 0.2f;
        featq[q * 9 + 2] = (float)c * (1.f / 64.f);
      }
      featq[q * 9 + foff + 0] = tmax;
      featq[q * 9 + foff + 1] = t5 * 0.2f;
      featq[q * 9 + foff + 2] = ssum * (1.f / 64.f);
    }
  }
}

__global__ __launch_bounds__(1024, 4) void sent_kernel(
    const float* __restrict__ doc, const short* __restrict__ qf,
    const float* __restrict__ qwv, const float* __restrict__ gaf,
    const short* __restrict__ Wf1, const float* __restrict__ b1,
    const short* __restrict__ Wf2, const float* __restrict__ b2,
    const float* __restrict__ m1w, const float* __restrict__ m1b,
    const float* __restrict__ m2w, const float* __restrict__ m2b,
    const float* __restrict__ ow, float* __restrict__ out)
{
  __shared__ short TB[256 * RS + 8];   // X1 rows 0..63 | Y1 64..127 | X2 128..191 | Y2 192..255
  __shared__ float invn[128];
  __shared__ float featb[576];         // 2 sentences x 32 q x 9

  const int tid = threadIdx.x, lane = tid & 63, w = tid >> 6;
  const int r = lane & 15, g = lane >> 4;
  const int mg = w & 3, sg = (w >> 2) & 1, ng = w >> 3;
  const int pq = mg + ((w >> 1) & 4);     // 0..7 pool-q group within sentence
  const int s2 = blockIdx.x * 2;

  short* Xb = TB + sg * 128 * RS;
  short* Yb = Xb + 64 * RS;
  float* SIMb = (float*)(Yb + RS);        // overlay on Y rows 1..14 (row 0 head stays zero)
  float* featq = featb + sg * 288;
  const float* invnp = invn + sg * 64;

  // ---- Phase A: zero pads + zero Y row-0 heads (kt=9 g=3 spill targets) + load + norms ----
  if (tid < 256) {
    short* p = TB + tid * RS + 300;
    *(short4_t*)p = (short4_t)0;
    *(short8*)(p + 4) = (short8)0;
  } else if (tid == 256) {
    *(short8*)(TB + 256 * RS) = (short8)0;      // end pad (Y2 row 63 spill)
  } else if (tid == 257) {
    *(short8*)(TB + 64 * RS) = (short8)0;       // Y1 row 0 cols 0..7 (X1 row 63 spill)
  } else if (tid == 258) {
    *(short8*)(TB + 192 * RS) = (short8)0;      // Y2 row 0 cols 0..7 (X2 row 63 spill)
  }
  {
    int row = tid >> 3, part = tid & 7;       // row 0..127
    int si = row >> 6, li = row & 63;
    const float* xr = doc + (size_t)(s2 + si) * 19200 + li * 300;
    short* xrow = TB + (si * 128 + li) * RS;
    float ssum = 0.f;
#pragma unroll
    for (int m = 0; m < 5; ++m) {
      int c = part * 8 + m * 64;
      if (c <= 292) {
        f32x4 u0 = *(const f32x4*)(xr + c);
        f32x4 u1 = *(const f32x4*)(xr + c + 4);
        short8 o;
#pragma unroll
        for (int j = 0; j < 4; ++j) {
          ssum += u0[j] * u0[j] + u1[j] * u1[j];
          o[j] = f2b(u0[j]); o[4 + j] = f2b(u1[j]);
        }
        *(short8*)(xrow + c) = o;
      } else if (c == 296) {
        f32x4 u0 = *(const f32x4*)(xr + 296);
        short4_t o;
#pragma unroll
        for (int j = 0; j < 4; ++j) { ssum += u0[j] * u0[j]; o[j] = f2b(u0[j]); }
        *(short4_t*)(xrow + 296) = o;
      }
    }
    ssum += __shfl_xor(ssum, 1);
    ssum += __shfl_xor(ssum, 2);
    ssum += __shfl_xor(ssum, 4);
    if (part == 0) invn[row] = rsqrtf(ssum);
  }
  __syncthreads();

  // ---- Phase B: sim_insens (one 16x16 tile per wave) ----
  sim_mfma(Xb, qf, SIMb, mg * 2 + ng, r, g, lane);
  __syncthreads();

  // ---- Phase C: pool oh + insens ----
  pool3(SIMb, invnp, featq, pq * 4, lane, 3, true);
  __syncthreads();

  // ---- Phase D: re-zero SIMb-trashed Y pad cols (rows 0..15 of each Y) + conv1 X->Y ----
  if (tid < 32) {
    short* p = TB + (((tid >> 4) * 128 + 64) + (tid & 15)) * RS + 300;
    *(short4_t*)p = (short4_t)0;
    *(short8*)(p + 4) = (short8)0;
  }
  conv_mfma(Xb, Yb, Wf1, b1, mg, ng, r, g, lane);
  __syncthreads();

  // ---- Phase E: conv2 Y->X ----
  conv_mfma(Yb, Xb, Wf2, b2, mg, ng, r, g, lane);
  __syncthreads();

  // ---- Phase F: ctx norms + sim_sens ----
  {
    int row = tid >> 3, part = tid & 7;
    const short* xrow = TB + ((row >> 6) * 128 + (row & 63)) * RS;
    float ssum = 0.f;
    for (int i = part * 8; i < 304; i += 64) {
      short8 hv = *(const short8*)(xrow + i);
#pragma unroll
      for (int j = 0; j < 8; ++j) { float f = b2f(hv[j]); ssum += f * f; }
    }
    ssum += __shfl_xor(ssum, 1);
    ssum += __shfl_xor(ssum, 2);
    ssum += __shfl_xor(ssum, 4);
    if (part == 0) invn[row] = rsqrtf(ssum);
  }
  sim_mfma(Xb, qf + 10240, SIMb, mg * 2 + ng, r, g, lane);
  __syncthreads();

  // ---- Phase G: pool sens ----
  pool3(SIMb, invnp, featq, pq * 4, lane, 6, false);
  __syncthreads();

  // ---- Phase H: MLP + weighted emit + sigmoid (waves 0 and 4) ----
  if ((w & 11) == 0) {
    float val = 0.f;
    if (lane < 32) {
      int q = lane;
      float o8 = m2b[0];
#pragma unroll
      for (int j = 0; j < 8; ++j) {
        float a = m1b[j];
#pragma unroll
        for (int f = 0; f < 9; ++f) a += m1w[j * 9 + f] * featq[q * 9 + f];
        a = leaky(a);
        o8 += m2w[j] * a;
      }
      val = o8 * qwv[q];
    }
    float tot = waveSum(val);
    if (lane == 0) {
      int s = s2 + sg;
      float emit = tot * (1.f / 32.f);
      float z = gaf[s * 3 + 0] * ow[0] + gaf[s * 3 + 1] * ow[1] +
                gaf[s * 3 + 2] * ow[2] + emit * ow[3];
      out[s] = 1.f / (1.f + expf(-z));
    }
  }
}

extern "C" void kernel_launch(void* const* d_in, const int* in_sizes, int n_in,
                              void* d_out, int out_size, void* d_ws, size_t ws_size,
                              hipStream_t stream)
{
  const float* doc  = (const float*)d_in[0];
  const float* qemb = (const float*)d_in[1];
  const float* qidf = (const float*)d_in[2];
  const float* gaf  = (const float*)d_in[3];
  const float* W1   = (const float*)d_in[4];
  const float* b1   = (const float*)d_in[5];
  const float* W2   = (const float*)d_in[6];
  const float* b2   = (const float*)d_in[7];
  const float* qww  = (const float*)d_in[8];
  const float* qwb  = (const float*)d_in[9];
  const float* m1w  = (const float*)d_in[10];
  const float* m1b  = (const float*)d_in[11];
  const float* m2w  = (const float*)d_in[12];
  const float* m2b  = (const float*)d_in[13];
  const float* ow   = (const float*)d_in[14];
  float* out = (float*)d_out;

  float* ws   = (float*)d_ws;
  float* qc1  = ws;                     // 9600 f32
  float* qctx = ws + 9600;              // 9600 f32
  float* qwv  = ws + 19200;             // 32 f32
  short* wsS  = (short*)(ws + 19232);   // 16B-aligned
  short* Wf1  = wsS;                    // 307200 bf16
  short* Wf2  = wsS + 307200;           // 307200 bf16
  short* qfS  = wsS + 614400;           // 20480 bf16

  wfrag_kernel<<<150, 256, 0, stream>>>(W1, Wf1);
  wfrag_kernel<<<150, 256, 0, stream>>>(W2, Wf2);
  qconv_kernel<<<300, 256, 0, stream>>>(qemb, W1, b1, qc1);
  qconv_kernel<<<300, 256, 0, stream>>>(qc1, W2, b2, qctx);
  qfinish_kernel<<<1, 256, 0, stream>>>(qemb, qctx, qidf, qww, qwb, qwv, qfS);
  sent_kernel<<<2048, 1024, 0, stream>>>(doc, qfS, qwv, gaf, Wf1, b1, Wf2, b2,
                                         m1w, m1b, m2w, m2b, ow, out);
}

// Round 9
// 649.385 us; speedup vs baseline: 1.0495x; 1.0495x over previous
//
#include <hip/hip_runtime.h>
#include <math.h>

typedef __attribute__((ext_vector_type(8))) short short8;
typedef __attribute__((ext_vector_type(4))) short short4_t;
typedef __attribute__((ext_vector_type(4))) float f32x4;

#define RS      312          // shorts per LDS tile row (624 B = 39*16B)
#define EPS_OH  0.999f

__device__ __forceinline__ float waveSum(float v) {
#pragma unroll
  for (int off = 32; off; off >>= 1) v += __shfl_xor(v, off);
  return v;
}
__device__ __forceinline__ float waveMax(float v) {
#pragma unroll
  for (int off = 32; off; off >>= 1) v = fmaxf(v, __shfl_xor(v, off));
  return v;
}
__device__ __forceinline__ float leaky(float x) { return fmaxf(x, 0.1f * x); }

__device__ __forceinline__ short f2b(float f) {
  unsigned u = __float_as_uint(f);
  unsigned r = (u + 0x7FFFu + ((u >> 16) & 1u)) >> 16;
  return (short)r;
}
__device__ __forceinline__ float b2f(short h) {
  return __uint_as_float(((unsigned)(unsigned short)h) << 16);
}

// ---------------- question-side conv block (fp32, tiny), 8 lanes per output ----------------
__global__ __launch_bounds__(256) void qconv_kernel(
    const float* __restrict__ x, const float* __restrict__ W,
    const float* __restrict__ b, float* __restrict__ y)
{
  int idx = blockIdx.x * 256 + threadIdx.x;
  if (idx >= 76800) return;
  int part = idx & 7, gid = idx >> 3;
  int o = gid % 300, l = gid / 300;
  const float* Wo = W + o * 900;
  float acc = 0.f;
  for (int i = part; i < 300; i += 8) {
    float x1 = x[l * 300 + i];
    float x0 = (l >= 1) ? x[(l - 1) * 300 + i] : 0.f;
    float x2 = (l <= 30) ? x[(l + 1) * 300 + i] : 0.f;
    acc += Wo[i * 3] * x0 + Wo[i * 3 + 1] * x1 + Wo[i * 3 + 2] * x2;
  }
  acc += __shfl_xor(acc, 1);
  acc += __shfl_xor(acc, 2);
  acc += __shfl_xor(acc, 4);
  if (part == 0) y[gid] = leaky(acc + b[o]) + x[gid];
}

// ---------------- q_weights softmax + normalized q fragments (bf16 A-layout) ----------------
__global__ __launch_bounds__(256) void qfinish_kernel(
    const float* __restrict__ qemb, const float* __restrict__ qctx,
    const float* __restrict__ qidf, const float* __restrict__ qww,
    const float* __restrict__ qwb,
    float* __restrict__ qwv, short* __restrict__ qf)
{
  __shared__ float inq[32], inqc[32], lg[32];
  int tid = threadIdx.x, lane = tid & 63, w = tid >> 6;
  int r = w * 8 + (lane >> 3), sub = lane & 7;
  float sq = 0.f, sqc = 0.f, dt = 0.f;
  for (int i = sub; i < 300; i += 8) {
    float a = qemb[r * 300 + i]; sq  += a * a;
    float c = qctx[r * 300 + i]; sqc += c * c;
    dt += c * qww[i];
  }
#pragma unroll
  for (int off = 4; off; off >>= 1) {
    sq  += __shfl_xor(sq, off);
    sqc += __shfl_xor(sqc, off);
    dt  += __shfl_xor(dt, off);
  }
  if (sub == 0) {
    inq[r] = rsqrtf(sq); inqc[r] = rsqrtf(sqc);
    lg[r] = dt + qidf[r] * qww[300] + qwb[0];
  }
  __syncthreads();
  if (w == 0) {
    float L = (lane < 32) ? lg[lane] : -1e30f;
    float m = L;
#pragma unroll
    for (int off = 32; off; off >>= 1) m = fmaxf(m, __shfl_xor(m, off));
    float e = (lane < 32) ? expf(L - m) : 0.f;
    float ssum = e;
#pragma unroll
    for (int off = 32; off; off >>= 1) ssum += __shfl_xor(ssum, off);
    if (lane < 32) qwv[lane] = e / ssum;
  }
  __syncthreads();
  for (int t = tid; t < 2560; t += 256) {
    int ln = t & 63;
    int rest = t >> 6;
    int kt = rest % 10; rest /= 10;
    int mt = rest & 1; int sflag = rest >> 1;
    const float* src  = sflag ? qctx : qemb;
    const float* innv = sflag ? inqc : inq;
    int q  = mt * 16 + (ln & 15);
    int i0 = kt * 32 + (ln >> 4) * 8;
    float iv = innv[q];
    short8 v;
#pragma unroll
    for (int j = 0; j < 8; ++j) {
      int i = i0 + j;
      v[j] = f2b((i < 300) ? src[q * 300 + i] * iv : 0.f);
    }
    *(short8*)(qf + (size_t)t * 8) = v;
  }
}

// ---------------- W (300,300,3) fp32 -> bf16 A-fragment layout ----------------
__global__ __launch_bounds__(256) void wfrag_kernel(
    const float* __restrict__ W, short* __restrict__ Wf)
{
  int t = blockIdx.x * 256 + threadIdx.x;
  if (t >= 38400) return;
  int lane = t & 63;
  int rest = t >> 6;
  int mt = rest % 20; rest /= 20;
  int kt = rest % 10; int tap = rest / 10;
  int o  = mt * 16 + (lane & 15);
  int i0 = kt * 32 + (lane >> 4) * 8;
  short8 v;
#pragma unroll
  for (int j = 0; j < 8; ++j) {
    int i = i0 + j;
    v[j] = f2b((o < 300 && i < 300) ? W[o * 900 + i * 3 + tap] : 0.f);
  }
  *(short8*)(Wf + (size_t)t * 8) = v;
}

// ---------------- fused per-sentence kernel helpers ----------------

// conv block, branch-free template: wave w owns mtiles {w, w+8, (w+16)}, all 4 ntiles.
// Fully unrolled kt x tap so LLVM can software-pipeline A(global/L2) and B(LDS) loads
// into the MFMA stream (round-8 evidence: VGPR=64 => no pipelining with guarded loops).
template <int NMT>
__device__ __forceinline__ void conv_mfma_t(
    const short* src, short* dst, const short* __restrict__ Wf,
    const float* __restrict__ bias, int w, int r, int g, int lane)
{
  f32x4 acc[NMT][4];
#pragma unroll
  for (int mi = 0; mi < NMT; ++mi)
#pragma unroll
    for (int nt = 0; nt < 4; ++nt) acc[mi][nt] = (f32x4){0.f, 0.f, 0.f, 0.f};

  const short* wl = Wf + (size_t)lane * 8;
  const int rm0 = (r == 0) ? 0 : (r - 1);        // tap0 row for nt=0 (clamped)
  const int rp3 = (r == 15) ? 63 : (48 + r + 1); // tap2 row for nt=3 (clamped)

#pragma unroll
  for (int kt = 0; kt < 10; ++kt) {
    const int koff = kt * 32 + g * 8;
#pragma unroll
    for (int tap = 0; tap < 3; ++tap) {
      short8 bf[4];
#pragma unroll
      for (int nt = 0; nt < 4; ++nt) {
        int l = nt * 16 + r;
        int rowi = (tap == 0) ? ((nt == 0) ? rm0 : (l - 1))
                 : (tap == 1) ? l
                              : ((nt == 3) ? rp3 : (l + 1));
        bf[nt] = *(const short8*)(src + rowi * RS + koff);
      }
      if (tap == 0) bf[0] = (r == 0)  ? (short8)0 : bf[0];   // position -1 -> 0
      if (tap == 2) bf[3] = (r == 15) ? (short8)0 : bf[3];   // position 64 -> 0
#pragma unroll
      for (int mi = 0; mi < NMT; ++mi) {
        const int mt = w + 8 * mi;
        short8 af = *(const short8*)(wl + (size_t)((tap * 10 + kt) * 20 + mt) * 512);
#pragma unroll
        for (int nt = 0; nt < 4; ++nt)
          acc[mi][nt] = __builtin_amdgcn_mfma_f32_16x16x32_bf16(af, bf[nt], acc[mi][nt], 0, 0, 0);
      }
    }
  }
#pragma unroll
  for (int mi = 0; mi < NMT; ++mi) {
    const int mt = w + 8 * mi;
    const int m0 = mt * 16 + g * 4;
    if (m0 < 300) {
      f32x4 bv = *(const f32x4*)(bias + m0);
#pragma unroll
      for (int nt = 0; nt < 4; ++nt) {
        int l = nt * 16 + r;
        short4_t resv = *(const short4_t*)(src + l * RS + m0);
        short4_t outv;
#pragma unroll
        for (int j = 0; j < 4; ++j) {
          float a = acc[mi][nt][j] + bv[j];
          a = leaky(a) + b2f(resv[j]);
          outv[j] = f2b(a);
        }
        *(short4_t*)(dst + l * RS + m0) = outv;
      }
    }
  }
}

// sim GEMM: one 16x16 tile per wave; SIMb[q][l] = normalized-q . src-col
__device__ __forceinline__ void sim_mfma(
    const short* src, const short* __restrict__ qf, float* SIMb,
    int ti, int r, int g, int lane)
{
  int smt = ti >> 2, snt = ti & 3;
  f32x4 acc = (f32x4){0.f, 0.f, 0.f, 0.f};
#pragma unroll
  for (int kt = 0; kt < 10; ++kt) {
    short8 bf = *(const short8*)(src + (snt * 16 + r) * RS + kt * 32 + g * 8);
    short8 af = *(const short8*)(qf + (size_t)((smt * 10 + kt) * 64 + lane) * 8);
    acc = __builtin_amdgcn_mfma_f32_16x16x32_bf16(af, bf, acc, 0, 0, 0);
  }
  int l = snt * 16 + r;
#pragma unroll
  for (int j = 0; j < 4; ++j)
    SIMb[(smt * 16 + g * 4 + j) * 68 + l] = acc[j];
}

// pooling for 4 q's per wave; results kept in registers (static indices)
__device__ __forceinline__ void pool3(
    const float* SIMb, const float* invn, int w, int lane,
    float* st, float* ohst)
{
#pragma unroll
  for (int qi = 0; qi < 4; ++qi) {
    int q = w * 4 + qi;
    float sim = SIMb[q * 68 + lane] * invn[lane];
    float ssum = waveSum(sim);
    float vv = sim, tmax = 0.f, t5 = 0.f;
#pragma unroll
    for (int it = 0; it < 5; ++it) {
      float m = waveMax(vv);
      if (it == 0) tmax = m;
      t5 += m;
      unsigned long long bb = __ballot(vv == m);
      if (lane == (int)__builtin_ctzll(bb)) vv = -3e38f;
    }
    if (ohst) {
      int c = __popcll(__ballot(sim > EPS_OH));
      ohst[qi * 3 + 0] = (c > 0) ? 1.f : 0.f;
      ohst[qi * 3 + 1] = (c < 5 ? (float)c : 5.f) * 0.2f;
      ohst[qi * 3 + 2] = (float)c * (1.f / 64.f);
    }
    st[qi * 3 + 0] = tmax;
    st[qi * 3 + 1] = t5 * 0.2f;
    st[qi * 3 + 2] = ssum * (1.f / 64.f);
  }
}

__device__ __forceinline__ void norms_lds(const short* Xb, float* invn, int tid) {
  int row = tid >> 3, part = tid & 7;
  float ssum = 0.f;
  for (int i = part * 8; i < 304; i += 64) {
    short8 hv = *(const short8*)(Xb + row * RS + i);
#pragma unroll
    for (int j = 0; j < 8; ++j) { float f = b2f(hv[j]); ssum += f * f; }
  }
  ssum += __shfl_xor(ssum, 1);
  ssum += __shfl_xor(ssum, 2);
  ssum += __shfl_xor(ssum, 4);
  if (part == 0) invn[row] = rsqrtf(ssum);
}

__global__ __launch_bounds__(512, 4) void sent_kernel(
    const float* __restrict__ doc, const short* __restrict__ qf,
    const float* __restrict__ qwv, const float* __restrict__ gaf,
    const short* __restrict__ Wf1, const float* __restrict__ b1,
    const short* __restrict__ Wf2, const float* __restrict__ b2,
    const float* __restrict__ m1w, const float* __restrict__ m1b,
    const float* __restrict__ m2w, const float* __restrict__ m2b,
    const float* __restrict__ ow, float* __restrict__ out)
{
  __shared__ short TB[128 * RS + 8];   // X rows 0..63, Y rows 64..127, 8-short end pad
  __shared__ float invn[64];
  __shared__ float featb[32 * 9];
  float* SIMb = (float*)(TB + 65 * RS);   // overlay on Y rows 1..14 (row 0 head stays zero)

  const int tid = threadIdx.x, lane = tid & 63, w = tid >> 6;
  const int r = lane & 15, g = lane >> 4;
  const int s = blockIdx.x;
  short* Xb = TB;
  short* Yb = TB + 64 * RS;

  // ---- Phase A: zero pads (disjoint bytes) + load+convert + inline fp32 norms ----
  if (tid < 128) {                       // cols 300..311 of every row
    short* p = TB + tid * RS + 300;
    *(short4_t*)p = (short4_t)0;
    *(short8*)(p + 4) = (short8)0;
  } else if (tid == 128) {               // Y row 0 cols 0..7 (sim/conv1 edge spill)
    *(short8*)(Yb) = (short8)0;
  } else if (tid == 129) {               // end pad (conv2 edge spill)
    *(short8*)(TB + 128 * RS) = (short8)0;
  }
  {
    int l = tid >> 3, part = tid & 7;
    const float* xr = doc + (size_t)s * 19200 + l * 300;
    float ssum = 0.f;
#pragma unroll
    for (int m = 0; m < 5; ++m) {
      int c = part * 8 + m * 64;
      if (c <= 292) {
        f32x4 u0 = *(const f32x4*)(xr + c);
        f32x4 u1 = *(const f32x4*)(xr + c + 4);
        short8 o;
#pragma unroll
        for (int j = 0; j < 4; ++j) {
          ssum += u0[j] * u0[j] + u1[j] * u1[j];
          o[j] = f2b(u0[j]); o[4 + j] = f2b(u1[j]);
        }
        *(short8*)(Xb + l * RS + c) = o;
      } else if (c == 296) {
        f32x4 u0 = *(const f32x4*)(xr + 296);
        short4_t o;
#pragma unroll
        for (int j = 0; j < 4; ++j) { ssum += u0[j] * u0[j]; o[j] = f2b(u0[j]); }
        *(short4_t*)(Xb + l * RS + 296) = o;
      }
    }
    ssum += __shfl_xor(ssum, 1);
    ssum += __shfl_xor(ssum, 2);
    ssum += __shfl_xor(ssum, 4);
    if (part == 0) invn[l] = rsqrtf(ssum);
  }
  __syncthreads();

  // ---- Phase B: sim_insens GEMM ----
  sim_mfma(Xb, qf, SIMb, w, r, g, lane);
  __syncthreads();

  // ---- Phase C: pool oh + insens -> registers ----
  float oh_st[12], ins_st[12], sens_st[12];
  pool3(SIMb, invn, w, lane, ins_st, oh_st);
  __syncthreads();

  // ---- Phase D: re-zero SIMb-contaminated pad cols (disjoint from conv1) + conv1 X->Y ----
  if (tid < 17) {
    short* p = Yb + (1 + tid) * RS + 300;
    *(short4_t*)p = (short4_t)0;
    *(short8*)(p + 4) = (short8)0;
  }
  if (w < 3) conv_mfma_t<3>(Xb, Yb, Wf1, b1, w, r, g, lane);
  else       conv_mfma_t<2>(Xb, Yb, Wf1, b1, w, r, g, lane);
  __syncthreads();

  // ---- Phase E: conv2 Y->X ----
  if (w < 3) conv_mfma_t<3>(Yb, Xb, Wf2, b2, w, r, g, lane);
  else       conv_mfma_t<2>(Yb, Xb, Wf2, b2, w, r, g, lane);
  __syncthreads();

  // ---- Phase F: ctx norms + sim_sens GEMM ----
  norms_lds(Xb, invn, tid);
  sim_mfma(Xb, qf + 10240, SIMb, w, r, g, lane);
  __syncthreads();

  // ---- Phase G: pool sens + write all feats ----
  pool3(SIMb, invn, w, lane, sens_st, (float*)0);
  if (lane == 0) {
#pragma unroll
    for (int qi = 0; qi < 4; ++qi) {
      int q = w * 4 + qi;
#pragma unroll
      for (int k = 0; k < 3; ++k) {
        featb[q * 9 + k]     = oh_st[qi * 3 + k];
        featb[q * 9 + 3 + k] = ins_st[qi * 3 + k];
        featb[q * 9 + 6 + k] = sens_st[qi * 3 + k];
      }
    }
  }
  __syncthreads();

  // ---- Phase H: MLP + weighted emit + sigmoid (wave 0) ----
  if (w == 0) {
    float val = 0.f;
    if (lane < 32) {
      int q = lane;
      float o8 = m2b[0];
#pragma unroll
      for (int j = 0; j < 8; ++j) {
        float a = m1b[j];
#pragma unroll
        for (int f = 0; f < 9; ++f) a += m1w[j * 9 + f] * featb[q * 9 + f];
        a = leaky(a);
        o8 += m2w[j] * a;
      }
      val = o8 * qwv[q];
    }
    float tot = waveSum(val);
    if (lane == 0) {
      float emit = tot * (1.f / 32.f);
      float z = gaf[s * 3 + 0] * ow[0] + gaf[s * 3 + 1] * ow[1] +
                gaf[s * 3 + 2] * ow[2] + emit * ow[3];
      out[s] = 1.f / (1.f + expf(-z));
    }
  }
}

extern "C" void kernel_launch(void* const* d_in, const int* in_sizes, int n_in,
                              void* d_out, int out_size, void* d_ws, size_t ws_size,
                              hipStream_t stream)
{
  const float* doc  = (const float*)d_in[0];
  const float* qemb = (const float*)d_in[1];
  const float* qidf = (const float*)d_in[2];
  const float* gaf  = (const float*)d_in[3];
  const float* W1   = (const float*)d_in[4];
  const float* b1   = (const float*)d_in[5];
  const float* W2   = (const float*)d_in[6];
  const float* b2   = (const float*)d_in[7];
  const float* qww  = (const float*)d_in[8];
  const float* qwb  = (const float*)d_in[9];
  const float* m1w  = (const float*)d_in[10];
  const float* m1b  = (const float*)d_in[11];
  const float* m2w  = (const float*)d_in[12];
  const float* m2b  = (const float*)d_in[13];
  const float* ow   = (const float*)d_in[14];
  float* out = (float*)d_out;

  float* ws   = (float*)d_ws;
  float* qc1  = ws;                     // 9600 f32
  float* qctx = ws + 9600;              // 9600 f32
  float* qwv  = ws + 19200;             // 32 f32
  short* wsS  = (short*)(ws + 19232);   // 16B-aligned
  short* Wf1  = wsS;                    // 307200 bf16
  short* Wf2  = wsS + 307200;           // 307200 bf16
  short* qfS  = wsS + 614400;           // 20480 bf16

  wfrag_kernel<<<150, 256, 0, stream>>>(W1, Wf1);
  wfrag_kernel<<<150, 256, 0, stream>>>(W2, Wf2);
  qconv_kernel<<<300, 256, 0, stream>>>(qemb, W1, b1, qc1);
  qconv_kernel<<<300, 256, 0, stream>>>(qc1, W2, b2, qctx);
  qfinish_kernel<<<1, 256, 0, stream>>>(qemb, qctx, qidf, qww, qwb, qwv, qfS);
  sent_kernel<<<4096, 512, 0, stream>>>(doc, qfS, qwv, gaf, Wf1, b1, Wf2, b2,
                                        m1w, m1b, m2w, m2b, ow, out);
}